// Round 10
// baseline (222.110 us; speedup 1.0000x reference)
//
#include <hip/hip_runtime.h>
#include <math.h>

// Problem constants (B=8, T=4096, D=1024, G=2, N=320, Cd=512)
#define M_ROWS 32768   // B*T
#define KDIM   1024    // D
#define GN     640     // G*N
#define NGRP   2
#define NCODES 320
#define CD     512

#define BM 32            // rows per block
#define BK 32            // k per step
#define NKK (KDIM / BK)  // 32
#define THREADS 256      // 4 waves, column-split: 80 cols each

typedef __attribute__((ext_vector_type(8))) short bf16x8;
typedef __attribute__((ext_vector_type(4))) float f32x4;

__device__ __forceinline__ unsigned short f2bf(float f) {
    unsigned u = __builtin_bit_cast(unsigned, f);
    return (unsigned short)((u + 0x7FFFu + ((u >> 16) & 1u)) >> 16);  // RNE
}
__device__ __forceinline__ unsigned pk2(float lo, float hi) {
    return (unsigned)f2bf(lo) | ((unsigned)f2bf(hi) << 16);
}

// ---- prepass: W[k][GN] fp32 -> Wt5 bf16 so each B-frag is one COALESCED
// 1KB wave load: Wt5[g][w][kk][nf][chunk(64)][8], chunk = l4*16 + (col&15),
// k = kk*32 + l4*8 + j, col = g*320 + w*80 + nf*16 + (col&15). Zeroes counts.
__global__ __launch_bounds__(256) void prep_kernel(const float* __restrict__ W,
                                                   unsigned short* __restrict__ Wt5,
                                                   int* __restrict__ counts) {
    const int k  = blockIdx.x;                  // 0..1023
    const int kk = k >> 5, l4s = (k >> 3) & 3, j = k & 7;
    for (int c = threadIdx.x; c < GN; c += 256) {
        int g  = c / NCODES;
        int cw = c % NCODES;
        int w  = cw / 80;
        int cl = cw % 80;
        int nf = cl >> 4, cm = cl & 15;
        size_t idx = (((((size_t)(g * 4 + w) * NKK + kk) * 5 + nf) * 64)
                      + (l4s * 16 + cm)) * 8 + j;
        Wt5[idx] = f2bf(W[(size_t)k * GN + c]);
    }
    if (blockIdx.x == 0)
        for (int i = threadIdx.x; i < GN; i += 256) counts[i] = 0;
}

// ---- fused GEMM + argmax + counts + gather. NO LDS staging, NO barriers in
// the K-loop: B-frags stream L2->regs (coalesced), x rows shared via L1/L2.
__global__ __launch_bounds__(THREADS, 4) void gemm_fused(
    const float* __restrict__ x,              // [M, K] fp32
    const float* __restrict__ gumbel,         // [M, GN] fp32
    const float* __restrict__ codebook,       // [G, N, CD] fp32
    const unsigned short* __restrict__ Wt5,   // retiled bf16 (prep_kernel)
    const float* __restrict__ bias,           // [GN]
    float* __restrict__ out,                  // [M, G*CD] fp32 (+ loss slot)
    int* __restrict__ counts)                 // [GN]
{
    __shared__ float pv[4][BM];
    __shared__ int   pi[4][BM];
    __shared__ int   idx_s[BM];

    const int tid  = threadIdx.x;
    const int wid  = tid >> 6;       // 0..3: column quarter of the group (80 cols)
    const int lane = tid & 63;
    const int l15  = lane & 15;
    const int l4   = lane >> 4;      // k-slot

    // block decode: bid = xcd + 8*(g + 2*rtl); both groups of a row-slice on one XCD
    const int b    = blockIdx.x;
    const int xcd  = b & 7;
    const int l    = b >> 3;         // 0..255
    const int g    = l & 1;
    const int rtl  = l >> 1;         // 0..127
    const int row0 = (xcd * 128 + rtl) * BM;

    f32x4 acc[2][5];
#pragma unroll
    for (int mf = 0; mf < 2; ++mf)
#pragma unroll
        for (int nf = 0; nf < 5; ++nf) acc[mf][nf] = (f32x4){0.f, 0.f, 0.f, 0.f};

    // A: per-lane x loads; lane serves rows (row0+l15) and (+16), k-slice l4*8.
    // All 4 waves read the same 32 rows -> L1/L2 absorbs the duplication.
    const float* ap0 = x + (size_t)(row0 + l15) * KDIM + l4 * 8;
    const float* ap1 = ap0 + 16 * KDIM;
    // B: this wave's contiguous 160 KB stream (32 kk x 5 frags x 1 KB), coalesced
    const char* wsrc = (const char*)Wt5 + (size_t)(g * 4 + wid) * (NKK * 5 * 1024)
                     + (size_t)lane * 16;

#pragma unroll 2
    for (int kk = 0; kk < NKK; ++kk) {
        // B-frags: 5 independent coalesced 1KB loads (deep ILP, L2-resident)
        const char* bp = wsrc + kk * 5120;
        bf16x8 bfr[5];
#pragma unroll
        for (int nf = 0; nf < 5; ++nf)
            bfr[nf] = *reinterpret_cast<const bf16x8*>(bp + nf * 1024);
        // A-frags: 4 float4 + pack to bf16
        const float* p0 = ap0 + kk * BK;
        const float* p1 = ap1 + kk * BK;
        float4 a0 = *reinterpret_cast<const float4*>(p0);
        float4 a1 = *reinterpret_cast<const float4*>(p0 + 4);
        float4 a2 = *reinterpret_cast<const float4*>(p1);
        float4 a3 = *reinterpret_cast<const float4*>(p1 + 4);
        union { bf16x8 v; unsigned u[4]; } w0, w1;
        w0.u[0] = pk2(a0.x, a0.y); w0.u[1] = pk2(a0.z, a0.w);
        w0.u[2] = pk2(a1.x, a1.y); w0.u[3] = pk2(a1.z, a1.w);
        w1.u[0] = pk2(a2.x, a2.y); w1.u[1] = pk2(a2.z, a2.w);
        w1.u[2] = pk2(a3.x, a3.y); w1.u[3] = pk2(a3.z, a3.w);
#pragma unroll
        for (int nf = 0; nf < 5; ++nf) {
            acc[0][nf] = __builtin_amdgcn_mfma_f32_16x16x32_bf16(w0.v, bfr[nf], acc[0][nf], 0, 0, 0);
            acc[1][nf] = __builtin_amdgcn_mfma_f32_16x16x32_bf16(w1.v, bfr[nf], acc[1][nf], 0, 0, 0);
        }
    }

    // ---- epilogue: + bias + gumbel, per-row argmax over this wave's 80 cols
    // C/D layout: col = l15, row-in-frag = l4*4 + reg
    const int hbase = wid * 80;               // n-offset within group
    float bv[5];
#pragma unroll
    for (int nf = 0; nf < 5; ++nf) bv[nf] = bias[g * NCODES + hbase + nf * 16 + l15];
#pragma unroll
    for (int mf = 0; mf < 2; ++mf) {
#pragma unroll
        for (int j = 0; j < 4; ++j) {
            const int lr = mf * 16 + l4 * 4 + j;
            const size_t r = row0 + lr;
            const float* grow = gumbel + r * GN + g * NCODES;
            float best = -INFINITY;
            int bn = 0;
#pragma unroll
            for (int nf = 0; nf < 5; ++nf) {
                int n = hbase + nf * 16 + l15;
                float v = acc[mf][nf][j] + bv[nf] + grow[n];
                if (v > best) { best = v; bn = n; }   // nf ascending -> first max kept
            }
#pragma unroll
            for (int m = 1; m < 16; m <<= 1) {
                float ov = __shfl_xor(best, m, 64);
                int   on = __shfl_xor(bn, m, 64);
                if (ov > best || (ov == best && on < bn)) { best = ov; bn = on; }
            }
            if (l15 == 0) { pv[wid][lr] = best; pi[wid][lr] = bn; }
        }
    }
    __syncthreads();

    // combine the 4 column-quarters (ascending cols, strict > keeps lower index)
    if (tid < BM) {
        float best = pv[0][tid];
        int   bn   = pi[0][tid];
#pragma unroll
        for (int w = 1; w < 4; ++w) {
            float v = pv[w][tid];
            if (v > best) { best = v; bn = pi[w][tid]; }
        }
        idx_s[tid] = bn;
        atomicAdd(&counts[g * NCODES + bn], 1);
    }
    __syncthreads();

    // ---- gather: this block's half-rows of out: 32 rows x 512 floats, coalesced
#pragma unroll
    for (int s = 0; s < 16; ++s) {
        int fi = tid + THREADS * s;   // 0..4095 float4
        int lr = fi >> 7;             // /128 float4 per row
        int d4 = fi & 127;
        int n  = idx_s[lr];
        float4 cv = *reinterpret_cast<const float4*>(
            &codebook[((size_t)g * NCODES + n) * CD + d4 * 4]);
        *reinterpret_cast<float4*>(
            &out[(size_t)(row0 + lr) * KDIM + (size_t)g * CD + d4 * 4]) = cv;
    }
}

__global__ void loss_kernel(const int* __restrict__ counts, float* __restrict__ out_loss) {
    __shared__ float red[256];
    float sum = 0.0f;
    for (int i = threadIdx.x; i < GN; i += 256) {
        float avg = (float)counts[i] * (1.0f / (float)M_ROWS);
        sum += avg * logf(avg + 1e-7f);
    }
    red[threadIdx.x] = sum;
    __syncthreads();
    for (int s = 128; s > 0; s >>= 1) {
        if (threadIdx.x < s) red[threadIdx.x] += red[threadIdx.x + s];
        __syncthreads();
    }
    if (threadIdx.x == 0) out_loss[0] = -red[0] * (1.0f / (float)NGRP);
}

extern "C" void kernel_launch(void* const* d_in, const int* in_sizes, int n_in,
                              void* d_out, int out_size, void* d_ws, size_t ws_size,
                              hipStream_t stream) {
    const float* x        = (const float*)d_in[0];
    const float* gumbel   = (const float*)d_in[1];
    const float* codebook = (const float*)d_in[2];
    const float* W        = (const float*)d_in[3];
    const float* bias     = (const float*)d_in[4];
    float* out = (float*)d_out;

    unsigned short* Wt5 = (unsigned short*)d_ws;              // 1.25 MB retiled
    int* counts = (int*)((char*)d_ws + 1310720 + 256);        // 2.5 KB

    prep_kernel<<<dim3(KDIM), dim3(256), 0, stream>>>(W, Wt5, counts);
    gemm_fused<<<dim3(2048), dim3(THREADS), 0, stream>>>(
        x, gumbel, codebook, Wt5, bias, out, counts);
    loss_kernel<<<dim3(1), dim3(256), 0, stream>>>(
        counts, out + (size_t)M_ROWS * KDIM);
}

// Round 11
// 142.205 us; speedup vs baseline: 1.5619x; 1.5619x over previous
//
#include <hip/hip_runtime.h>
#include <math.h>

// Problem constants (B=8, T=4096, D=1024, G=2, N=320, Cd=512)
#define M_ROWS 32768   // B*T
#define KDIM   1024    // D
#define GN     640     // G*N
#define NGRP   2
#define NCODES 320
#define CD     512

#define BMR 64           // rows per block
#define BK 64            // k per tile
#define NT (KDIM / BK)   // 16
#define THREADS 256      // 4 waves: 2 (M) x 2 (N); wave tile 32 x 160
#define BSLAB 40960      // B tile bytes: 8 seg x 320 col x 16 B

typedef __attribute__((ext_vector_type(8))) short bf16x8;
typedef __attribute__((ext_vector_type(4))) float f32x4;

__device__ __forceinline__ unsigned short f2bf(float f) {
    unsigned u = __builtin_bit_cast(unsigned, f);
    return (unsigned short)((u + 0x7FFFu + ((u >> 16) & 1u)) >> 16);  // RNE
}
__device__ __forceinline__ unsigned pk2(float lo, float hi) {
    return (unsigned)f2bf(lo) | ((unsigned)f2bf(hi) << 16);
}
// async global->LDS, 16B/lane; LDS dest = wave-uniform base + lane*16
__device__ __forceinline__ void gll16(const void* g, void* l) {
    __builtin_amdgcn_global_load_lds(
        (const __attribute__((address_space(1))) unsigned int*)g,
        (__attribute__((address_space(3))) unsigned int*)l, 16, 0, 0);
}

// ---- prepass: W[k][GN] fp32 -> Wt bf16 per-(ktile,group) 40KB slabs laid out
// exactly as the B LDS tile: [seg(8)][col(320)][8 bf16], seg = (k>>3)&7,
// j = k&7, t = k>>6. A wave's B-frag ds_read is then 16 consecutive chunks.
__global__ __launch_bounds__(256) void prep_kernel(const float* __restrict__ W,
                                                   unsigned short* __restrict__ Wt,
                                                   int* __restrict__ counts) {
    const int k = blockIdx.x;                    // 0..1023
    const int t = k >> 6, seg = (k >> 3) & 7, j = k & 7;
    for (int c = threadIdx.x; c < GN; c += 256) {
        int g  = c / NCODES;
        int cw = c % NCODES;
        size_t idx = ((((size_t)t * 2 + g) * 8 + seg) * NCODES + cw) * 8 + j;
        Wt[idx] = f2bf(W[(size_t)k * GN + c]);
    }
    if (blockIdx.x == 0)
        for (int i = threadIdx.x; i < GN; i += 256) counts[i] = 0;
}

// ---- fused MFMA GEMM + argmax + counts + gather.
// 64x320 tile, BK=64: 40 MFMA / 24 ds_read per wave per k-step, 16 k-steps.
// 49 KB LDS -> 3 blocks/CU co-resident; grid 1024 = 4 work-blocks/CU.
__global__ __launch_bounds__(THREADS, 3) void gemm_fused(
    const float* __restrict__ x,              // [M, K] fp32
    const float* __restrict__ gumbel,         // [M, GN] fp32
    const float* __restrict__ codebook,       // [G, N, CD] fp32
    const unsigned short* __restrict__ Wt,    // retiled bf16 (prep_kernel)
    const float* __restrict__ bias,           // [GN]
    float* __restrict__ out,                  // [M, G*CD] fp32 (+ loss slot)
    int* __restrict__ counts)                 // [GN]
{
    __shared__ __align__(16) char Bs[BSLAB];    // 40 KB B tile (one k-step)
    __shared__ __align__(16) char As[8192];     // 8 KB A tile bf16 (XOR-swizzled)
    __shared__ float pv[2][BMR];
    __shared__ int   pi[2][BMR];
    __shared__ int   idx_s[BMR];

    const int tid  = threadIdx.x;
    const int wid  = tid >> 6;       // 0..3
    const int lane = tid & 63;
    const int l15  = lane & 15;
    const int l4   = lane >> 4;      // k-slot within 32-k half
    const int wn   = wid & 1;        // col half: 160 cols
    const int wm   = wid >> 1;       // row half: 32 rows

    // block decode: bid = xcd + 8*(g + 2*rtl); both groups of a row panel on
    // one XCD (x rows L2-shared). 1024 = 8 XCD x 128 (bijective).
    const int b    = blockIdx.x;
    const int xcd  = b & 7;
    const int l    = b >> 3;         // 0..127
    const int g    = l & 1;
    const int rtl  = l >> 1;         // 0..63
    const int row0 = (xcd * 64 + rtl) * BMR;

    f32x4 acc[2][10];
#pragma unroll
    for (int mf = 0; mf < 2; ++mf)
#pragma unroll
        for (int nf = 0; nf < 10; ++nf) acc[mf][nf] = (f32x4){0.f, 0.f, 0.f, 0.f};

    // ---- A staging geometry (reg-stage + XOR-swizzled ds_write_b64):
    // thread covers rows (tid>>4)+16i, i=0..3, k-quad q = tid&15 of each row.
    // chunk (seg = q>>1) holds k = seg*8..seg*8+7; half = q&1.
    // LDS addr = (seg*64 + (row ^ seg))*16 + half*8  — banks verified distinct.
    const int q     = tid & 15;
    const int aseg  = q >> 1;
    const int ahalf = q & 1;
    const int arow  = tid >> 4;              // +16i
    const float* xbase = x + (size_t)(row0 + arow) * KDIM + q * 4;

    // ---- B staging: wave wid DMAs bytes wid*10240..+10239 of the 40KB slab
    const char* wtbase = (const char*)Wt + (size_t)g * BSLAB
                       + wid * 10240 + (size_t)lane * 16;

#define STAGE_B(T) do {                                                 \
        const char* s_ = wtbase + (size_t)(T) * (2 * BSLAB);            \
        char* d_ = Bs + wid * 10240;                                    \
        _Pragma("unroll")                                               \
        for (int i_ = 0; i_ < 10; ++i_)                                 \
            gll16(s_ + i_ * 1024, d_ + i_ * 1024);                      \
    } while (0)

#define LOAD_A(T) do {                                                  \
        _Pragma("unroll")                                               \
        for (int i_ = 0; i_ < 4; ++i_)                                  \
            xa[i_] = *reinterpret_cast<const float4*>(                  \
                xbase + (size_t)(16 * i_) * KDIM + (T) * BK);           \
    } while (0)

#define WRITE_A() do {                                                  \
        _Pragma("unroll")                                               \
        for (int i_ = 0; i_ < 4; ++i_) {                                \
            int row_ = arow + 16 * i_;                                  \
            uint2 w_ = { pk2(xa[i_].x, xa[i_].y),                       \
                         pk2(xa[i_].z, xa[i_].w) };                     \
            *reinterpret_cast<uint2*>(                                  \
                As + (aseg * 64 + (row_ ^ aseg)) * 16 + ahalf * 8) = w_;\
        }                                                               \
    } while (0)

#define COMPUTE() do {                                                  \
        _Pragma("unroll")                                               \
        for (int ks = 0; ks < 2; ++ks) {                                \
            const int seg_ = ks * 4 + l4;                               \
            bf16x8 afr[2];                                              \
            _Pragma("unroll")                                           \
            for (int mf = 0; mf < 2; ++mf) {                            \
                int row_ = wm * 32 + mf * 16 + l15;                     \
                afr[mf] = *reinterpret_cast<const bf16x8*>(             \
                    As + (seg_ * 64 + (row_ ^ seg_)) * 16);             \
            }                                                           \
            _Pragma("unroll")                                           \
            for (int nf = 0; nf < 10; ++nf) {                           \
                int col_ = wn * 160 + nf * 16 + l15;                    \
                bf16x8 bfr = *reinterpret_cast<const bf16x8*>(          \
                    Bs + (seg_ * NCODES + col_) * 16);                  \
                acc[0][nf] = __builtin_amdgcn_mfma_f32_16x16x32_bf16(   \
                    afr[0], bfr, acc[0][nf], 0, 0, 0);                  \
                acc[1][nf] = __builtin_amdgcn_mfma_f32_16x16x32_bf16(   \
                    afr[1], bfr, acc[1][nf], 0, 0, 0);                  \
            }                                                           \
        }                                                               \
    } while (0)

    float4 xa[4];
    // prologue: tile 0
    LOAD_A(0);
    STAGE_B(0);
    WRITE_A();
    __syncthreads();                 // tile 0 resident (drains DMA + ds_write)

    for (int t = 0; t < NT; ++t) {
        if (t + 1 < NT) LOAD_A(t + 1);   // issue-early: flies under compute
        COMPUTE();                        // 40 MFMA + 24 ds_read per wave
        if (t + 1 < NT) {
            __syncthreads();              // all waves done reading tile t
            STAGE_B(t + 1);
            WRITE_A();
            __syncthreads();              // tile t+1 resident
        }
    }

    // ---- epilogue: + bias + gumbel, per-row argmax over this wave's 160 cols
    // C/D layout: col = l15, row-in-frag = l4*4 + reg
#pragma unroll
    for (int mf = 0; mf < 2; ++mf) {
#pragma unroll
        for (int j = 0; j < 4; ++j) {
            const int lr = wm * 32 + mf * 16 + l4 * 4 + j;
            const size_t r = row0 + lr;
            const float* grow = gumbel + r * GN + g * NCODES;
            const float* brow = bias + g * NCODES;
            float best = -INFINITY;
            int bn = 0;
#pragma unroll
            for (int nf = 0; nf < 10; ++nf) {
                int n = wn * 160 + nf * 16 + l15;
                float v = acc[mf][nf][j] + brow[n] + grow[n];
                if (v > best) { best = v; bn = n; }   // nf ascending -> first max kept
            }
#pragma unroll
            for (int m = 1; m < 16; m <<= 1) {
                float ov = __shfl_xor(best, m, 64);
                int   on = __shfl_xor(bn, m, 64);
                if (ov > best || (ov == best && on < bn)) { best = ov; bn = on; }
            }
            if (l15 == 0) { pv[wn][lr] = best; pi[wn][lr] = bn; }
        }
    }
    __syncthreads();

    // combine halves: wn=1 cols all > wn=0 cols; strict > keeps lower index
    if (tid < BMR) {
        float v0 = pv[0][tid], v1 = pv[1][tid];
        int n = (v1 > v0) ? pi[1][tid] : pi[0][tid];
        idx_s[tid] = n;
        atomicAdd(&counts[g * NCODES + n], 1);
    }
    __syncthreads();

    // ---- gather: this block's half-rows of out: 64 rows x 512 floats, coalesced
#pragma unroll
    for (int s = 0; s < 32; ++s) {
        int fi = tid + THREADS * s;   // 0..8191 float4
        int lr = fi >> 7;             // /128 float4 per row
        int d4 = fi & 127;
        int n  = idx_s[lr];
        float4 cv = *reinterpret_cast<const float4*>(
            &codebook[((size_t)g * NCODES + n) * CD + d4 * 4]);
        *reinterpret_cast<float4*>(
            &out[(size_t)(row0 + lr) * KDIM + (size_t)g * CD + d4 * 4]) = cv;
    }
#undef STAGE_B
#undef LOAD_A
#undef WRITE_A
#undef COMPUTE
}

__global__ void loss_kernel(const int* __restrict__ counts, float* __restrict__ out_loss) {
    __shared__ float red[256];
    float sum = 0.0f;
    for (int i = threadIdx.x; i < GN; i += 256) {
        float avg = (float)counts[i] * (1.0f / (float)M_ROWS);
        sum += avg * logf(avg + 1e-7f);
    }
    red[threadIdx.x] = sum;
    __syncthreads();
    for (int s = 128; s > 0; s >>= 1) {
        if (threadIdx.x < s) red[threadIdx.x] += red[threadIdx.x + s];
        __syncthreads();
    }
    if (threadIdx.x == 0) out_loss[0] = -red[0] * (1.0f / (float)NGRP);
}

extern "C" void kernel_launch(void* const* d_in, const int* in_sizes, int n_in,
                              void* d_out, int out_size, void* d_ws, size_t ws_size,
                              hipStream_t stream) {
    const float* x        = (const float*)d_in[0];
    const float* gumbel   = (const float*)d_in[1];
    const float* codebook = (const float*)d_in[2];
    const float* W        = (const float*)d_in[3];
    const float* bias     = (const float*)d_in[4];
    float* out = (float*)d_out;

    unsigned short* Wt = (unsigned short*)d_ws;               // 1.31 MB retiled
    int* counts = (int*)((char*)d_ws + 1310720 + 256);        // 2.5 KB

    prep_kernel<<<dim3(KDIM), dim3(256), 0, stream>>>(W, Wt, counts);
    gemm_fused<<<dim3(1024), dim3(THREADS), 0, stream>>>(
        x, gumbel, codebook, Wt, bias, out, counts);
    loss_kernel<<<dim3(1), dim3(256), 0, stream>>>(
        counts, out + (size_t)M_ROWS * KDIM);
}